// Round 4
// baseline (559.186 us; speedup 1.0000x reference)
//
#include <hip/hip_runtime.h>
#include <stdint.h>

#define NTOK 4096   // B*S tokens
#define DIM  1024   // model dim
#define NEXP 8      // experts
#define HID  4096   // expert hidden
#define CAP  1024   // capacity per expert

typedef __bf16 bf16x8 __attribute__((ext_vector_type(8)));
typedef float  f32x4  __attribute__((ext_vector_type(4)));

__device__ __forceinline__ unsigned short f2bf(float f) {
  unsigned int u = __float_as_uint(f);
  return (unsigned short)((u + 0x7fffu + ((u >> 16) & 1u)) >> 16);  // RNE
}

__device__ __forceinline__ float bf2f(unsigned int bits16) {
  return __uint_as_float(bits16 << 16);
}

__device__ __forceinline__ void load_lds16(const void* g, void* l) {
  __builtin_amdgcn_global_load_lds(
      (__attribute__((address_space(1))) void*)g,
      (__attribute__((address_space(3))) void*)l,
      16, 0, 0);
}

// ---------------- 1. gating ----------------
__global__ void gating_kernel(const float* __restrict__ x, const float* __restrict__ wg,
                              int* __restrict__ tok_e, float* __restrict__ tok_g) {
  const int t = blockIdx.x;
  const int l = threadIdx.x;
  float acc[NEXP];
#pragma unroll
  for (int e = 0; e < NEXP; ++e) acc[e] = 0.f;

  const float4* x4  = (const float4*)(x + (size_t)t * DIM);
  const float4* wg4 = (const float4*)wg;
#pragma unroll
  for (int i = 0; i < 4; ++i) {
    int dq = i * 64 + l;
    float4 xv = x4[dq];
    float xs[4] = {xv.x, xv.y, xv.z, xv.w};
#pragma unroll
    for (int c = 0; c < 4; ++c) {
      int d = dq * 4 + c;
      float4 wa = wg4[d * 2], wb = wg4[d * 2 + 1];
      acc[0] += xs[c] * wa.x; acc[1] += xs[c] * wa.y;
      acc[2] += xs[c] * wa.z; acc[3] += xs[c] * wa.w;
      acc[4] += xs[c] * wb.x; acc[5] += xs[c] * wb.y;
      acc[6] += xs[c] * wb.z; acc[7] += xs[c] * wb.w;
    }
  }
#pragma unroll
  for (int off = 32; off; off >>= 1)
#pragma unroll
    for (int e = 0; e < NEXP; ++e) acc[e] += __shfl_xor(acc[e], off);

  if (l == 0) {
    float m = acc[0];
#pragma unroll
    for (int e = 1; e < NEXP; ++e) m = fmaxf(m, acc[e]);
    float p[NEXP];
#pragma unroll
    for (int e = 0; e < NEXP; ++e) p[e] = __expf(acc[e] - m);
    int e0 = 0; float b0 = p[0];
#pragma unroll
    for (int e = 1; e < NEXP; ++e) if (p[e] > b0) { b0 = p[e]; e0 = e; }
    int e1 = -1; float b1v = -1.f;
#pragma unroll
    for (int e = 0; e < NEXP; ++e) if (e != e0 && p[e] > b1v) { b1v = p[e]; e1 = e; }
    float inv = 1.f / (b0 + b1v);
    tok_e[2 * t] = e0; tok_e[2 * t + 1] = e1;
    tok_g[2 * t] = b0 * inv; tok_g[2 * t + 1] = b1v * inv;
  }
}

// ---------------- 2. GShard slot-major cumsum ----------------
__global__ void scan_kernel(const int* __restrict__ tok_e, int* __restrict__ tok_loc,
                            int* __restrict__ slot_map) {
  const int l = threadIdx.x;
  const unsigned long long below = (1ull << l) - 1ull;
  int base[NEXP];
#pragma unroll
  for (int e = 0; e < NEXP; ++e) base[e] = 0;

  int nxt = tok_e[((0 * 64 + l) & (NTOK - 1)) * 2 + ((0 * 64 + l) >> 12)];
  for (int it = 0; it < 128; ++it) {
    int e = nxt;
    if (it + 1 < 128) {
      int g2 = (it + 1) * 64 + l;
      nxt = tok_e[(g2 & (NTOK - 1)) * 2 + (g2 >> 12)];
    }
    int loc = 0;
#pragma unroll
    for (int ex = 0; ex < NEXP; ++ex) {
      unsigned long long msk = __ballot(e == ex);
      int off = __popcll(msk & below);
      if (e == ex) loc = base[ex] + off;
      base[ex] += __popcll(msk);
    }
    int g = it * 64 + l;
    int k = g >> 12, t = g & (NTOK - 1);
    bool valid = loc < CAP;
    tok_loc[t * 2 + k] = valid ? loc : -1;
    if (valid) slot_map[e * CAP + loc] = t;
  }
#pragma unroll
  for (int ex = 0; ex < NEXP; ++ex) {
    int c = base[ex] < CAP ? base[ex] : CAP;
    for (int i = c + l; i < CAP; i += 64) slot_map[ex * CAP + i] = -1;
  }
}

// ---------------- 3. dispatch: gather x rows -> disp[E,CAP,D] bf16 ----------------
__global__ void dispatch_kernel(const float* __restrict__ x, const int* __restrict__ slot_map,
                                unsigned short* __restrict__ disp) {
  const int s = blockIdx.x;
  const int tid = threadIdx.x;
  int t = slot_map[s];
  uint2 o;
  if (t >= 0) {
    float4 v = ((const float4*)(x + (size_t)t * DIM))[tid];
    o.x = (unsigned)f2bf(v.x) | ((unsigned)f2bf(v.y) << 16);
    o.y = (unsigned)f2bf(v.z) | ((unsigned)f2bf(v.w) << 16);
  } else {
    o.x = 0u; o.y = 0u;
  }
  ((uint2*)(disp + (size_t)s * DIM))[tid] = o;
}

// ---------------- 4. transpose fp32 [R,C] -> bf16 [C,R] per expert ----------------
// 256 threads, 64col x 128row tile: per-wave stores are 4 x 256B contiguous runs
__global__ void transpose_cvt(const float* __restrict__ in, unsigned short* __restrict__ out,
                              int R, int C) {
  __shared__ float tile[128][65];
  const int e = blockIdx.z;
  const float* inp = in + (size_t)e * R * C;
  unsigned short* outp = out + (size_t)e * R * C;
  const int c0 = blockIdx.x * 64, r0 = blockIdx.y * 128;
  const int t = threadIdx.x;
#pragma unroll
  for (int i = 0; i < 8; ++i) {
    int idx = i * 256 + t;
    int r = idx >> 4, c4 = (idx & 15) * 4;
    float4 v = *(const float4*)(inp + (size_t)(r0 + r) * C + c0 + c4);
    tile[r][c4 + 0] = v.x; tile[r][c4 + 1] = v.y;
    tile[r][c4 + 2] = v.z; tile[r][c4 + 3] = v.w;
  }
  __syncthreads();
#pragma unroll
  for (int i = 0; i < 4; ++i) {
    int idx = i * 256 + t;            // 1024 items: (col, 8-row group)
    int c = idx >> 4, r8 = (idx & 15) * 8;
    unsigned short s[8];
#pragma unroll
    for (int j = 0; j < 8; ++j) s[j] = f2bf(tile[r8 + j][c]);
    uint4 o;
    o.x = (unsigned)s[0] | ((unsigned)s[1] << 16);
    o.y = (unsigned)s[2] | ((unsigned)s[3] << 16);
    o.z = (unsigned)s[4] | ((unsigned)s[5] << 16);
    o.w = (unsigned)s[6] | ((unsigned)s[7] << 16);
    *(uint4*)(outp + (size_t)(c0 + c) * R + r0 + r8) = o;
  }
}

// ---------------- 5/6. bf16 MFMA GEMM: m97-style 128x128, BK=32, 4 blocks/CU ----
// A [M=1024][K] bf16, B [N][K] bf16, C [M][N] bf16 (bias fp32 along N).
// 256 threads = 4 waves (2x2), each wave owns 64x64 via 4x4 x 16x16x32 MFMA.
// BK=32 halves LDS to 32 KiB (dbuf As/Bs 8 KiB each x2) so FOUR blocks
// co-reside per CU (VGPR capped <=128 via launch_bounds) -> 16 waves/CU.
// Cross-BLOCK wave overlap hides the per-iter __syncthreads vmcnt-drain that
// capped the 1-block/CU schedules at ~700 TF (R1/R3 post-mortem).
// LDS swizzle (BK=32: 4 chunks of 16B/row): phys chunk = logical ^ (row&3),
// pre-applied on the global source column (gload_lds dest must stay linear);
// fragment reads XOR it back. Frag row&3 == lane&3; staged row&3 == (lane>>2)&3.
template <bool RELU>
__global__ __launch_bounds__(256, 4)
void gemm_kernel(const unsigned short* __restrict__ A, const unsigned short* __restrict__ B,
                 const float* __restrict__ bias, unsigned short* __restrict__ C,
                 int N, int K) {
  __shared__ __align__(16) unsigned short As[2][128 * 32];
  __shared__ __align__(16) unsigned short Bs[2][128 * 32];

  // bijective XCD swizzle (grid % 8 == 0 for both instantiations); keeps each
  // expert's B panels resident in one XCD's L2.
  int bid = blockIdx.x;
  const int cpx = (int)gridDim.x >> 3;
  bid = (bid & 7) * cpx + (bid >> 3);
  const int ntn = N >> 7;           // N/128
  const int per_e = 8 * ntn;        // mt = 1024/128 = 8
  const int e = bid / per_e;
  const int rb = bid - e * per_e;
  const int mtile = rb / ntn;
  const int ntile = rb - mtile * ntn;

  A += (size_t)e * 1024 * K;
  B += (size_t)e * N * K;
  bias += (size_t)e * N;
  C += (size_t)e * 1024 * N;
  const int m0 = mtile * 128;
  const int n0 = ntile * 128;

  const int tid = threadIdx.x;
  const int wave = tid >> 6, lane = tid & 63;
  const int wm = wave >> 1, wn = wave & 1;
  const int quad = lane >> 4;

  // staging: 4 lanes per 64B row; wave covers 16 rows per round, 2 rounds.
  // phys chunk = lane&3; it loads swizzled logical chunk (lane&3)^(row&3).
  const int srow = lane >> 2;
  const int scol = ((lane & 3) ^ (srow & 3)) * 8;
  const unsigned short* gA = A + (size_t)(m0 + wave * 16 + srow) * K + scol;
  const unsigned short* gB = B + (size_t)(n0 + wave * 16 + srow) * K + scol;

  f32x4 acc[4][4] = {};

  // fragment reads: logical chunk = quad (k = quad*8+e), row&3 = lane&3
  const int coff = (quad ^ (lane & 3)) * 8;
  const int arowb = (wm * 64 + (lane & 15)) * 32;
  const int browb = (wn * 64 + (lane & 15)) * 32;

  // prologue: fill buffer 0 (2 rounds x 64 rows per operand)
#pragma unroll
  for (int i = 0; i < 2; ++i) {
    load_lds16(gA + (size_t)i * 64 * K, &As[0][(i * 64 + wave * 16) * 32]);
    load_lds16(gB + (size_t)i * 64 * K, &Bs[0][(i * 64 + wave * 16) * 32]);
  }
  gA += 32; gB += 32;

  const int nIter = K >> 5;
  for (int t = 0; t < nIter; ++t) {
    const int cur = t & 1;
    __syncthreads();   // implicit vmcnt(0): buf cur staged; buf cur^1 readers done
    if (t + 1 < nIter) {
#pragma unroll
      for (int i = 0; i < 2; ++i) {
        load_lds16(gA + (size_t)i * 64 * K, &As[cur ^ 1][(i * 64 + wave * 16) * 32]);
        load_lds16(gB + (size_t)i * 64 * K, &Bs[cur ^ 1][(i * 64 + wave * 16) * 32]);
      }
      gA += 32; gB += 32;
    }
    bf16x8 af[4], bfr[4];
#pragma unroll
    for (int i = 0; i < 4; ++i)
      af[i] = *reinterpret_cast<const bf16x8*>(&As[cur][arowb + i * 512 + coff]);
#pragma unroll
    for (int j = 0; j < 4; ++j)
      bfr[j] = *reinterpret_cast<const bf16x8*>(&Bs[cur][browb + j * 512 + coff]);
#pragma unroll
    for (int i = 0; i < 4; ++i)
#pragma unroll
      for (int j = 0; j < 4; ++j)
        acc[i][j] = __builtin_amdgcn_mfma_f32_16x16x32_bf16(af[i], bfr[j], acc[i][j], 0, 0, 0);
  }

  // ---- epilogue: wave-private LDS restage -> coalesced dwordx4 stores ----
  // 2 passes of 32 rows each (scratch 32x72 shorts/wave fits the 32 KiB LDS)
  __syncthreads();  // all waves done reading As/Bs
  unsigned short* scr = (wave < 2 ? &As[0][0] : &Bs[0][0]) + (wave & 1) * 2304;
  const int lc = lane & 15;
  const int erow = lane >> 3;
  const int ecol = (lane & 7) * 8;
#pragma unroll
  for (int p = 0; p < 2; ++p) {
#pragma unroll
    for (int j = 0; j < 4; ++j) {
      float bj = bias[n0 + wn * 64 + j * 16 + lc];
#pragma unroll
      for (int ii = 0; ii < 2; ++ii) {
#pragma unroll
        for (int rr = 0; rr < 4; ++rr) {
          float v = acc[p * 2 + ii][j][rr] + bj;
          if (RELU) v = fmaxf(v, 0.f);
          scr[(ii * 16 + quad * 4 + rr) * 72 + j * 16 + lc] = f2bf(v);
        }
      }
    }
    __asm__ volatile("s_waitcnt lgkmcnt(0)" ::: "memory");  // wave-internal LDS RAW
    unsigned short* Cbase = C + (size_t)(m0 + wm * 64 + p * 32) * N + n0 + wn * 64;
#pragma unroll
    for (int pp = 0; pp < 4; ++pp) {
      uint4 v = *(const uint4*)&scr[(pp * 8 + erow) * 72 + ecol];
      *(uint4*)&Cbase[(size_t)(pp * 8 + erow) * N + ecol] = v;
    }
    // next pass's scalar writes are same-wave, in-order after these reads
  }
}

// ---------------- 7. combine: gate-weighted gather (bf16 expert out) ----------------
__global__ void combine_kernel(const unsigned short* __restrict__ outb,
                               const int* __restrict__ tok_e, const int* __restrict__ tok_loc,
                               const float* __restrict__ tok_g, float* __restrict__ y) {
  const int t = blockIdx.x;
  const int tid = threadIdx.x;  // 0..255, 4 bf16 each
  int e0 = tok_e[2 * t], e1 = tok_e[2 * t + 1];
  int l0 = tok_loc[2 * t], l1 = tok_loc[2 * t + 1];
  float g0 = tok_g[2 * t], g1 = tok_g[2 * t + 1];
  float ax = 0.f, ay = 0.f, az = 0.f, aw = 0.f;
  if (l0 >= 0) {
    uint2 u = ((const uint2*)(outb + ((size_t)e0 * CAP + l0) * DIM))[tid];
    ax += g0 * bf2f(u.x & 0xffffu); ay += g0 * __uint_as_float(u.x & 0xffff0000u);
    az += g0 * bf2f(u.y & 0xffffu); aw += g0 * __uint_as_float(u.y & 0xffff0000u);
  }
  if (l1 >= 0) {
    uint2 u = ((const uint2*)(outb + ((size_t)e1 * CAP + l1) * DIM))[tid];
    ax += g1 * bf2f(u.x & 0xffffu); ay += g1 * __uint_as_float(u.x & 0xffff0000u);
    az += g1 * bf2f(u.y & 0xffffu); aw += g1 * __uint_as_float(u.y & 0xffff0000u);
  }
  float4 o; o.x = ax; o.y = ay; o.z = az; o.w = aw;
  ((float4*)(y + (size_t)t * DIM))[tid] = o;
}

extern "C" void kernel_launch(void* const* d_in, const int* in_sizes, int n_in,
                              void* d_out, int out_size, void* d_ws, size_t ws_size,
                              hipStream_t stream) {
  const float* x  = (const float*)d_in[0];
  const float* wg = (const float*)d_in[1];
  const float* w1 = (const float*)d_in[2];
  const float* b1 = (const float*)d_in[3];
  const float* w2 = (const float*)d_in[4];
  const float* b2 = (const float*)d_in[5];
  float* y = (float*)d_out;

  char* ws = (char*)d_ws;
  int*   tok_e    = (int*)(ws);
  int*   tok_loc  = (int*)(ws + 32768);
  float* tok_g    = (float*)(ws + 65536);
  int*   slot_map = (int*)(ws + 98304);
  unsigned short* disp = (unsigned short*)(ws + 131072);                      // 16 MiB
  unsigned short* wbuf = (unsigned short*)(ws + 131072 + (16ull << 20));      // 64 MiB
  unsigned short* h    = (unsigned short*)(ws + 131072 + (80ull << 20));      // 64 MiB
  unsigned short* outb = (unsigned short*)(ws + 131072 + (144ull << 20));     // 16 MiB

  gating_kernel<<<NTOK, 64, 0, stream>>>(x, wg, tok_e, tok_g);
  scan_kernel<<<1, 64, 0, stream>>>(tok_e, tok_loc, slot_map);
  dispatch_kernel<<<NEXP * CAP, 256, 0, stream>>>(x, slot_map, disp);
  // w1 [E][D][H] -> wbuf [E][H][D] bf16
  transpose_cvt<<<dim3(HID / 64, DIM / 128, NEXP), 256, 0, stream>>>(w1, wbuf, DIM, HID);
  // h = relu(disp @ w1 + b1): M=1024, N=HID, K=DIM; 8*8*32 = 2048 blocks
  gemm_kernel<true><<<NEXP * 8 * (HID / 128), 256, 0, stream>>>(disp, wbuf, b1, h, HID, DIM);
  // w2 [E][H][D] -> wbuf [E][D][H] bf16
  transpose_cvt<<<dim3(DIM / 64, HID / 128, NEXP), 256, 0, stream>>>(w2, wbuf, HID, DIM);
  // out = h @ w2 + b2: M=1024, N=DIM, K=HID; 8*8*8 = 512 blocks
  gemm_kernel<false><<<NEXP * 8 * (DIM / 128), 256, 0, stream>>>(h, wbuf, b2, outb, DIM, HID);
  combine_kernel<<<NTOK, 256, 0, stream>>>(outb, tok_e, tok_loc, tok_g, y);
}

// Round 5
// 516.889 us; speedup vs baseline: 1.0818x; 1.0818x over previous
//
#include <hip/hip_runtime.h>
#include <stdint.h>

#define NTOK 4096   // B*S tokens
#define DIM  1024   // model dim
#define NEXP 8      // experts
#define HID  4096   // expert hidden
#define CAP  1024   // capacity per expert

typedef __bf16 bf16x8 __attribute__((ext_vector_type(8)));
typedef float  f32x4  __attribute__((ext_vector_type(4)));

__device__ __forceinline__ unsigned short f2bf(float f) {
  unsigned int u = __float_as_uint(f);
  return (unsigned short)((u + 0x7fffu + ((u >> 16) & 1u)) >> 16);  // RNE
}

__device__ __forceinline__ float bf2f(unsigned int bits16) {
  return __uint_as_float(bits16 << 16);
}

__device__ __forceinline__ void load_lds16(const void* g, void* l) {
  __builtin_amdgcn_global_load_lds(
      (__attribute__((address_space(1))) void*)g,
      (__attribute__((address_space(3))) void*)l,
      16, 0, 0);
}

// ---------------- 1. gating ----------------
__global__ void gating_kernel(const float* __restrict__ x, const float* __restrict__ wg,
                              int* __restrict__ tok_e, float* __restrict__ tok_g) {
  const int t = blockIdx.x;
  const int l = threadIdx.x;
  float acc[NEXP];
#pragma unroll
  for (int e = 0; e < NEXP; ++e) acc[e] = 0.f;

  const float4* x4  = (const float4*)(x + (size_t)t * DIM);
  const float4* wg4 = (const float4*)wg;
#pragma unroll
  for (int i = 0; i < 4; ++i) {
    int dq = i * 64 + l;
    float4 xv = x4[dq];
    float xs[4] = {xv.x, xv.y, xv.z, xv.w};
#pragma unroll
    for (int c = 0; c < 4; ++c) {
      int d = dq * 4 + c;
      float4 wa = wg4[d * 2], wb = wg4[d * 2 + 1];
      acc[0] += xs[c] * wa.x; acc[1] += xs[c] * wa.y;
      acc[2] += xs[c] * wa.z; acc[3] += xs[c] * wa.w;
      acc[4] += xs[c] * wb.x; acc[5] += xs[c] * wb.y;
      acc[6] += xs[c] * wb.z; acc[7] += xs[c] * wb.w;
    }
  }
#pragma unroll
  for (int off = 32; off; off >>= 1)
#pragma unroll
    for (int e = 0; e < NEXP; ++e) acc[e] += __shfl_xor(acc[e], off);

  if (l == 0) {
    float m = acc[0];
#pragma unroll
    for (int e = 1; e < NEXP; ++e) m = fmaxf(m, acc[e]);
    float p[NEXP];
#pragma unroll
    for (int e = 0; e < NEXP; ++e) p[e] = __expf(acc[e] - m);
    int e0 = 0; float b0 = p[0];
#pragma unroll
    for (int e = 1; e < NEXP; ++e) if (p[e] > b0) { b0 = p[e]; e0 = e; }
    int e1 = -1; float b1v = -1.f;
#pragma unroll
    for (int e = 0; e < NEXP; ++e) if (e != e0 && p[e] > b1v) { b1v = p[e]; e1 = e; }
    float inv = 1.f / (b0 + b1v);
    tok_e[2 * t] = e0; tok_e[2 * t + 1] = e1;
    tok_g[2 * t] = b0 * inv; tok_g[2 * t + 1] = b1v * inv;
  }
}

// ---------------- 2. GShard slot-major cumsum ----------------
__global__ void scan_kernel(const int* __restrict__ tok_e, int* __restrict__ tok_loc,
                            int* __restrict__ slot_map) {
  const int l = threadIdx.x;
  const unsigned long long below = (1ull << l) - 1ull;
  int base[NEXP];
#pragma unroll
  for (int e = 0; e < NEXP; ++e) base[e] = 0;

  int nxt = tok_e[((0 * 64 + l) & (NTOK - 1)) * 2 + ((0 * 64 + l) >> 12)];
  for (int it = 0; it < 128; ++it) {
    int e = nxt;
    if (it + 1 < 128) {
      int g2 = (it + 1) * 64 + l;
      nxt = tok_e[(g2 & (NTOK - 1)) * 2 + (g2 >> 12)];
    }
    int loc = 0;
#pragma unroll
    for (int ex = 0; ex < NEXP; ++ex) {
      unsigned long long msk = __ballot(e == ex);
      int off = __popcll(msk & below);
      if (e == ex) loc = base[ex] + off;
      base[ex] += __popcll(msk);
    }
    int g = it * 64 + l;
    int k = g >> 12, t = g & (NTOK - 1);
    bool valid = loc < CAP;
    tok_loc[t * 2 + k] = valid ? loc : -1;
    if (valid) slot_map[e * CAP + loc] = t;
  }
#pragma unroll
  for (int ex = 0; ex < NEXP; ++ex) {
    int c = base[ex] < CAP ? base[ex] : CAP;
    for (int i = c + l; i < CAP; i += 64) slot_map[ex * CAP + i] = -1;
  }
}

// ---------------- 3. dispatch: gather x rows -> disp[E,CAP,D] bf16 ----------------
__global__ void dispatch_kernel(const float* __restrict__ x, const int* __restrict__ slot_map,
                                unsigned short* __restrict__ disp) {
  const int s = blockIdx.x;
  const int tid = threadIdx.x;
  int t = slot_map[s];
  uint2 o;
  if (t >= 0) {
    float4 v = ((const float4*)(x + (size_t)t * DIM))[tid];
    o.x = (unsigned)f2bf(v.x) | ((unsigned)f2bf(v.y) << 16);
    o.y = (unsigned)f2bf(v.z) | ((unsigned)f2bf(v.w) << 16);
  } else {
    o.x = 0u; o.y = 0u;
  }
  ((uint2*)(disp + (size_t)s * DIM))[tid] = o;
}

// ---------------- 4. transpose fp32 [R,C] -> bf16 [C,R] per expert ----------------
// 256 threads, 64col x 128row tile: per-wave stores are 4 x 256B contiguous runs
__global__ void transpose_cvt(const float* __restrict__ in, unsigned short* __restrict__ out,
                              int R, int C) {
  __shared__ float tile[128][65];
  const int e = blockIdx.z;
  const float* inp = in + (size_t)e * R * C;
  unsigned short* outp = out + (size_t)e * R * C;
  const int c0 = blockIdx.x * 64, r0 = blockIdx.y * 128;
  const int t = threadIdx.x;
#pragma unroll
  for (int i = 0; i < 8; ++i) {
    int idx = i * 256 + t;
    int r = idx >> 4, c4 = (idx & 15) * 4;
    float4 v = *(const float4*)(inp + (size_t)(r0 + r) * C + c0 + c4);
    tile[r][c4 + 0] = v.x; tile[r][c4 + 1] = v.y;
    tile[r][c4 + 2] = v.z; tile[r][c4 + 3] = v.w;
  }
  __syncthreads();
#pragma unroll
  for (int i = 0; i < 4; ++i) {
    int idx = i * 256 + t;            // 1024 items: (col, 8-row group)
    int c = idx >> 4, r8 = (idx & 15) * 8;
    unsigned short s[8];
#pragma unroll
    for (int j = 0; j < 8; ++j) s[j] = f2bf(tile[r8 + j][c]);
    uint4 o;
    o.x = (unsigned)s[0] | ((unsigned)s[1] << 16);
    o.y = (unsigned)s[2] | ((unsigned)s[3] << 16);
    o.z = (unsigned)s[4] | ((unsigned)s[5] << 16);
    o.w = (unsigned)s[6] | ((unsigned)s[7] << 16);
    *(uint4*)(outp + (size_t)(c0 + c) * R + r0 + r8) = o;
  }
}

// ---------------- 5/6. bf16 MFMA GEMM: 3-deep LDS ring, 1 barrier/K-tile ---------
// A [M=1024][K] bf16, B [N][K] bf16, C [M][N] bf16 (bias fp32 along N).
// BM=128, BN=256, BK=64. 512 threads = 8 waves (2M x 4N), 64x64 out per wave
// via 4x4 x 16x16x32 MFMA. LDS: 3 full A-tiles (16KiB) + 3 B-tiles (32KiB)
// = 144 KiB ring. Stage runs TWO K-tiles ahead of compute -> each stage has
// ~2 tiles (~4000cy) before its forcing wait: nothing exposed. Exactly ONE
// s_barrier + one counted vmcnt(6) per K-tile; no phases; compiler owns the
// ds_read<->MFMA interleave via per-use lgkmcnt (its strength, per m97 asm).
// Slot safety: stage target (t+2)%3 == (t-1)%3, whose readers finished before
// the previous barrier. Visibility: each wave's vmcnt forces its OWN 6 loads
// of tile t+1 at end of iter t; the barrier then publishes collectively.
// LDS swizzle (verified R1/R3): phys 16B chunk = logical ^ (row&7), applied on
// the global source column; fragment reads XOR it back (frag row&7 == lane&7).
template <bool RELU>
__global__ __launch_bounds__(512, 1)
void gemm3(const unsigned short* __restrict__ A, const unsigned short* __restrict__ B,
           const float* __restrict__ bias, unsigned short* __restrict__ C,
           int N, int K) {
  extern __shared__ __align__(16) unsigned short smem[];
  unsigned short* As = smem;            // 3 x 128*64
  unsigned short* Bs = smem + 3 * 8192; // 3 x 256*64

  // bijective XCD swizzle (grid % 8 == 0 for both instantiations)
  int bid = blockIdx.x;
  const int cpx = (int)gridDim.x >> 3;
  bid = (bid & 7) * cpx + (bid >> 3);
  const int ntn = N >> 8;           // N/256
  const int per_e = 8 * ntn;        // M/BM = 8
  const int e = bid / per_e;
  const int rb = bid - e * per_e;
  const int mtile = rb / ntn;
  const int ntile = rb - mtile * ntn;

  A += (size_t)e * 1024 * K;
  B += (size_t)e * N * K;
  bias += (size_t)e * N;
  C += (size_t)e * 1024 * N;
  const int m0 = mtile * 128;
  const int n0 = ntile * 256;

  const int tid = threadIdx.x;
  const int w = tid >> 6, lane = tid & 63;
  const int wm = w >> 2, wn = w & 3;
  const int quad = lane >> 4;
  const int l15 = lane & 15;

  // staging: thread covers row w*8 + (lane>>3) (+ q*64), phys chunk lane&7,
  // loading swizzled logical chunk (lane&7)^(row&7); row&7 == lane>>3.
  const int srow = lane >> 3;
  const int scol = ((lane & 7) ^ srow) * 8;
  const unsigned short* gA = A + (size_t)(m0 + w * 8 + srow) * K + scol;
  const unsigned short* gB = B + (size_t)(n0 + w * 8 + srow) * K + scol;
  const int lbase = w * 512;   // w*8 rows * 64 elems

  // fragment reads: logical chunk = quad + kk*4, row&7 = lane&7
  int coff[2];
  coff[0] = ((quad + 0) ^ (lane & 7)) * 8;
  coff[1] = ((quad + 4) ^ (lane & 7)) * 8;
  const int arow = (wm * 64 + l15) * 64;
  const int brow = (wn * 64 + l15) * 64;

  f32x4 acc[4][4] = {};
  const int nt = K >> 6;

#define STAGE(T, BUF)                                                           \
  { _Pragma("unroll")                                                           \
    for (int q_ = 0; q_ < 2; ++q_)                                              \
      load_lds16(gA + (size_t)(q_ * 64) * K + (size_t)(T) * 64,                 \
                 &As[(BUF) * 8192 + lbase + q_ * 4096]);                        \
    _Pragma("unroll")                                                           \
    for (int q_ = 0; q_ < 4; ++q_)                                              \
      load_lds16(gB + (size_t)(q_ * 64) * K + (size_t)(T) * 64,                 \
                 &Bs[(BUF) * 16384 + lbase + q_ * 4096]); }

  // prologue: stage tiles 0 and 1; force tile 0; publish
  STAGE(0, 0);
  STAGE(1, 1);
  asm volatile("s_waitcnt vmcnt(6)" ::: "memory");
  __builtin_amdgcn_s_barrier();
  __builtin_amdgcn_sched_barrier(0);

  int cur = 0;
  for (int t = 0; t < nt; ++t) {
    const bool s2 = (t + 2) < nt;
    if (s2) {
      int nx2 = cur - 1; if (nx2 < 0) nx2 = 2;   // (t+2)%3 == (t-1)%3
      STAGE(t + 2, nx2);
    }
    // ds-read tile t fragments (16 x b128), then 32 MFMA; compiler interleaves
    bf16x8 af[4][2], bfr[4][2];
#pragma unroll
    for (int f = 0; f < 4; ++f)
#pragma unroll
      for (int kk = 0; kk < 2; ++kk)
        af[f][kk] = *(const bf16x8*)&As[cur * 8192 + arow + f * 1024 + coff[kk]];
#pragma unroll
    for (int j = 0; j < 4; ++j)
#pragma unroll
      for (int kk = 0; kk < 2; ++kk)
        bfr[j][kk] = *(const bf16x8*)&Bs[cur * 16384 + brow + j * 1024 + coff[kk]];
    __builtin_amdgcn_s_setprio(1);
#pragma unroll
    for (int kk = 0; kk < 2; ++kk)
#pragma unroll
      for (int i = 0; i < 4; ++i)
#pragma unroll
        for (int j = 0; j < 4; ++j)
          acc[i][j] = __builtin_amdgcn_mfma_f32_16x16x32_bf16(af[i][kk], bfr[j][kk],
                                                              acc[i][j], 0, 0, 0);
    __builtin_amdgcn_s_setprio(0);
    if (s2) { asm volatile("s_waitcnt vmcnt(6)" ::: "memory"); }
    else    { asm volatile("s_waitcnt vmcnt(0)" ::: "memory"); }
    __builtin_amdgcn_s_barrier();
    __builtin_amdgcn_sched_barrier(0);
    ++cur; if (cur == 3) cur = 0;
  }
#undef STAGE

  // ---- epilogue: wave-private LDS restage -> coalesced dwordx4 stores ----
  // After the final barrier all waves' ds_reads are architecturally complete,
  // so each wave may scribble its private 64x72-short scratch region.
  unsigned short* scr = smem + w * 4608;
#pragma unroll
  for (int j = 0; j < 4; ++j) {
    float bj = bias[n0 + wn * 64 + j * 16 + l15];
#pragma unroll
    for (int i = 0; i < 4; ++i)
#pragma unroll
      for (int rr = 0; rr < 4; ++rr) {
        float v = acc[i][j][rr] + bj;
        if (RELU) v = fmaxf(v, 0.f);
        scr[(i * 16 + quad * 4 + rr) * 72 + j * 16 + l15] = f2bf(v);
      }
  }
  __asm__ volatile("s_waitcnt lgkmcnt(0)" ::: "memory");  // wave-internal LDS RAW
  const int erow = lane >> 3;
  const int ecol = (lane & 7) * 8;
  unsigned short* Cbase = C + (size_t)(m0 + wm * 64) * N + n0 + wn * 64;
#pragma unroll
  for (int p = 0; p < 8; ++p) {
    uint4 v = *(const uint4*)&scr[(p * 8 + erow) * 72 + ecol];
    *(uint4*)&Cbase[(size_t)(p * 8 + erow) * N + ecol] = v;
  }
}

// ---------------- 7. combine: gate-weighted gather (bf16 expert out) ----------------
__global__ void combine_kernel(const unsigned short* __restrict__ outb,
                               const int* __restrict__ tok_e, const int* __restrict__ tok_loc,
                               const float* __restrict__ tok_g, float* __restrict__ y) {
  const int t = blockIdx.x;
  const int tid = threadIdx.x;  // 0..255, 4 bf16 each
  int e0 = tok_e[2 * t], e1 = tok_e[2 * t + 1];
  int l0 = tok_loc[2 * t], l1 = tok_loc[2 * t + 1];
  float g0 = tok_g[2 * t], g1 = tok_g[2 * t + 1];
  float ax = 0.f, ay = 0.f, az = 0.f, aw = 0.f;
  if (l0 >= 0) {
    uint2 u = ((const uint2*)(outb + ((size_t)e0 * CAP + l0) * DIM))[tid];
    ax += g0 * bf2f(u.x & 0xffffu); ay += g0 * __uint_as_float(u.x & 0xffff0000u);
    az += g0 * bf2f(u.y & 0xffffu); aw += g0 * __uint_as_float(u.y & 0xffff0000u);
  }
  if (l1 >= 0) {
    uint2 u = ((const uint2*)(outb + ((size_t)e1 * CAP + l1) * DIM))[tid];
    ax += g1 * bf2f(u.x & 0xffffu); ay += g1 * __uint_as_float(u.x & 0xffff0000u);
    az += g1 * bf2f(u.y & 0xffffu); aw += g1 * __uint_as_float(u.y & 0xffff0000u);
  }
  float4 o; o.x = ax; o.y = ay; o.z = az; o.w = aw;
  ((float4*)(y + (size_t)t * DIM))[tid] = o;
}

extern "C" void kernel_launch(void* const* d_in, const int* in_sizes, int n_in,
                              void* d_out, int out_size, void* d_ws, size_t ws_size,
                              hipStream_t stream) {
  const float* x  = (const float*)d_in[0];
  const float* wg = (const float*)d_in[1];
  const float* w1 = (const float*)d_in[2];
  const float* b1 = (const float*)d_in[3];
  const float* w2 = (const float*)d_in[4];
  const float* b2 = (const float*)d_in[5];
  float* y = (float*)d_out;

  char* ws = (char*)d_ws;
  int*   tok_e    = (int*)(ws);
  int*   tok_loc  = (int*)(ws + 32768);
  float* tok_g    = (float*)(ws + 65536);
  int*   slot_map = (int*)(ws + 98304);
  unsigned short* disp = (unsigned short*)(ws + 131072);                      // 16 MiB
  unsigned short* wbuf = (unsigned short*)(ws + 131072 + (16ull << 20));      // 64 MiB
  unsigned short* h    = (unsigned short*)(ws + 131072 + (80ull << 20));      // 64 MiB
  unsigned short* outb = (unsigned short*)(ws + 131072 + (144ull << 20));     // 16 MiB

  // one-time: allow 144 KiB dynamic LDS for the ring GEMMs
  static int att = 0;
  if (!att) {
    (void)hipFuncSetAttribute(reinterpret_cast<const void*>(&gemm3<true>),
                              hipFuncAttributeMaxDynamicSharedMemorySize, 147456);
    (void)hipFuncSetAttribute(reinterpret_cast<const void*>(&gemm3<false>),
                              hipFuncAttributeMaxDynamicSharedMemorySize, 147456);
    att = 1;
  }

  gating_kernel<<<NTOK, 64, 0, stream>>>(x, wg, tok_e, tok_g);
  scan_kernel<<<1, 64, 0, stream>>>(tok_e, tok_loc, slot_map);
  dispatch_kernel<<<NEXP * CAP, 256, 0, stream>>>(x, slot_map, disp);
  // w1 [E][D][H] -> wbuf [E][H][D] bf16
  transpose_cvt<<<dim3(HID / 64, DIM / 128, NEXP), 256, 0, stream>>>(w1, wbuf, DIM, HID);
  // h = relu(disp @ w1 + b1): M=1024, N=HID, K=DIM; 8*8*16 = 1024 blocks
  gemm3<true><<<NEXP * 8 * (HID / 256), 512, 147456, stream>>>(disp, wbuf, b1, h, HID, DIM);
  // w2 [E][H][D] -> wbuf [E][D][H] bf16
  transpose_cvt<<<dim3(DIM / 64, HID / 128, NEXP), 256, 0, stream>>>(w2, wbuf, HID, DIM);
  // out = h @ w2 + b2: M=1024, N=DIM, K=HID; 8*8*4 = 256 blocks
  gemm3<false><<<NEXP * 8 * (DIM / 256), 512, 147456, stream>>>(h, wbuf, b2, outb, DIM, HID);
  combine_kernel<<<NTOK, 256, 0, stream>>>(outb, tok_e, tok_loc, tok_g, y);
}